// Round 5
// baseline (16.541 us; speedup 1.0000x reference)
//
#include <hip/hip_runtime.h>

typedef short  bf16x8 __attribute__((ext_vector_type(8)));
typedef float  f32x4  __attribute__((ext_vector_type(4)));

#define HP 4
#define SENT 0x5F3C2A1Du

// ---------------------------------------------------------------------------
// Single fused kernel: one block per (n, i) center-row. 224 blocks x 640 thr.
//
// Phase 1 (10 waves, one row each, zero cross-wave coupling): wave w stages
//   row w (w=0..8 -> B rows i-4..i+4, w=9 -> A row i). Lane = w-coordinate;
//   64 raw fp32 loads into regs (max MLP), per-lane ss accumulation (norms
//   applied AFTER MFMA: dot(a^,b^) = raw_dot * inva[j] * invb[j']), RTN to
//   bf16, ds_write_b128 into padded LDS tiles [w][72].
//
// Phase 2 (8 waves in parallel): wave w = band m (=w&3) x col-tile ti (=w>>2),
//   col tile ntv = m+ti (ntv==4 -> idle). 9 di x 2 MFMA = 18 MFMAs per wave.
//   s/sx accumulators merge additively across the wave pair in LDS (log comes
//   after the merge), then 64 parallel logs (1/lane) -> block partial.
//
// Finish: block publishes (SENT<<32 | f32bits) to a 64-bit slot (agent scope,
//   self-tagged -> no fence pairing, poison-proof). Block 0 wave 0 spins on
//   all 224 slots (all blocks co-resident: 1 block/CU, 224 < 256 CUs), sums
//   in fixed order, resets slots to 0, writes d_out. One dispatch total.
// ---------------------------------------------------------------------------
__global__ __launch_bounds__(640) void fused_kernel(const float* __restrict__ A,
                                                    const float* __restrict__ B,
                                                    unsigned long long* __restrict__ slots,
                                                    float* __restrict__ out) {
    __shared__ ushort bt[9][64][72];   // 82,944 B raw-bf16 B rows
    __shared__ ushort at[64][72];      //  9,216 B raw-bf16 A row
    __shared__ float  binv[9][64];     //  2,304 B
    __shared__ float  ainv_s[64];      //    256 B
    __shared__ float  s_lds[8][16];    //    512 B
    __shared__ float  sx_lds[8][16];   //    512 B

    // Bijective XCD swizzle (224 = 8 * 28): i-neighbors share an L2
    const int b0 = blockIdx.x;
    const int b  = (b0 & 7) * 28 + (b0 >> 3);
    const int n  = b / 56;
    const int i  = b - n * 56 + HP;          // 4..59
    const int t  = threadIdx.x, wib = t >> 6, l = t & 63;

    // ---- Phase 1: wave wib stages its single row
    {
        const int r = wib;                   // 0..9, wave-uniform
        const int hrow = (r == 9) ? i : (i - HP + r);
        const float* src = ((r == 9) ? A : B) + (size_t)n * 262144 + (size_t)hrow * 64 + l;
        ushort* dst = ((r == 9) ? &at[0][0] : &bt[r][0][0]) + l * 72;

        float v[64];
        #pragma unroll
        for (int c = 0; c < 64; ++c) v[c] = src[(size_t)c * 4096];

        float ss0 = 0.f, ss1 = 0.f, ss2 = 0.f, ss3 = 0.f;
        #pragma unroll
        for (int c = 0; c < 64; c += 4) {
            ss0 = fmaf(v[c],   v[c],   ss0);
            ss1 = fmaf(v[c+1], v[c+1], ss1);
            ss2 = fmaf(v[c+2], v[c+2], ss2);
            ss3 = fmaf(v[c+3], v[c+3], ss3);
        }
        #pragma unroll
        for (int c0 = 0; c0 < 64; c0 += 8) {
            uint pk[4];
            #pragma unroll
            for (int q = 0; q < 4; ++q) {
                uint u0 = __float_as_uint(v[c0 + 2*q]);     u0 = (u0 + 0x7FFFu + ((u0 >> 16) & 1)) >> 16;
                uint u1 = __float_as_uint(v[c0 + 2*q + 1]); u1 = (u1 + 0x7FFFu + ((u1 >> 16) & 1)) >> 16;
                pk[q] = u0 | (u1 << 16);
            }
            *(uint4*)(dst + c0) = *(const uint4*)pk;   // 16B aligned (144|16, 2*c0|16)
        }
        const float inv = 1.0f / (sqrtf((ss0 + ss1) + (ss2 + ss3)) + 1e-8f);
        if (r == 9) ainv_s[l] = inv; else binv[r][l] = inv;
    }
    __syncthreads();

    // ---- Phase 2: 8 waves, wave = (band m, col-tile ti)
    const int lo = l & 15, hi = l >> 4;
    if (wib < 8) {
        const int m   = wib & 3, ti = wib >> 2;
        const int ntv = m + ti;                  // 0..4 (4 = no tile)
        const int j0  = HP + m * 16;
        const int arow_l = min(j0 + lo, 63);     // clamped lanes feed only masked rows
        const bf16x8 a0 = *(const bf16x8*)&at[arow_l][hi * 8];
        const bf16x8 a1 = *(const bf16x8*)&at[arow_l][hi * 8 + 32];

        int jrow[4]; float av[4];
        #pragma unroll
        for (int r = 0; r < 4; ++r) {
            jrow[r] = j0 + hi * 4 + r;
            av[r]   = ainv_s[min(jrow[r], 63)];
        }

        float s_acc[4]  = {0.f, 0.f, 0.f, 0.f};
        float sx_acc[4] = {0.f, 0.f, 0.f, 0.f};

        if (ntv < 4) {
            const int col = ntv * 16 + lo;
            float vm[4];
            #pragma unroll
            for (int r = 0; r < 4; ++r) {
                int d = col - jrow[r];
                vm[r] = (jrow[r] < 60 && d >= -HP && d <= HP) ? 1.0f : 0.0f;
            }
            #pragma unroll
            for (int di = 0; di < 9; ++di) {
                const ushort* q = &bt[di][col][hi * 8];
                const bf16x8 bq0 = *(const bf16x8*)q;
                const bf16x8 bq1 = *(const bf16x8*)(q + 32);
                f32x4 acc = __builtin_amdgcn_mfma_f32_16x16x32_bf16(a0, bq0,
                                (f32x4){0.f, 0.f, 0.f, 0.f}, 0, 0, 0);
                acc = __builtin_amdgcn_mfma_f32_16x16x32_bf16(a1, bq1, acc, 0, 0, 0);
                const float bi = binv[di][col];
                #pragma unroll
                for (int r = 0; r < 4; ++r) {
                    float p = acc[r] * (av[r] * bi);
                    float e = __expf(p);
                    s_acc[r]  = fmaf(vm[r], e, s_acc[r]);
                    sx_acc[r] = fmaf(vm[r], p, sx_acc[r]);
                }
            }
        }
        // reduce across the 16 lanes (cols) sharing each output row
        #pragma unroll
        for (int r = 0; r < 4; ++r) {
            #pragma unroll
            for (int off = 1; off < 16; off <<= 1) {
                s_acc[r]  += __shfl_xor(s_acc[r],  off);
                sx_acc[r] += __shfl_xor(sx_acc[r], off);
            }
        }
        if (lo == 0) {
            #pragma unroll
            for (int r = 0; r < 4; ++r) {
                s_lds[wib][hi * 4 + r]  = s_acc[r];
                sx_lds[wib][hi * 4 + r] = sx_acc[r];
            }
        }
    }
    __syncthreads();

    // ---- Per-block finish + global publish (wave 0 only)
    if (wib == 0) {
        const int m2 = l >> 4, rib = l & 15;     // lane l <-> j = HP + l
        float contrib = 0.f;
        if (l < 56) {
            float s  = s_lds[m2][rib]  + s_lds[m2 + 4][rib];
            float sx = sx_lds[m2][rib] + sx_lds[m2 + 4][rib];
            contrib = 81.0f * __logf(s) - sx;
        }
        #pragma unroll
        for (int off = 32; off; off >>= 1) contrib += __shfl_xor(contrib, off);
        if (l == 0) {
            unsigned long long payload =
                ((unsigned long long)SENT << 32) | (unsigned long long)__float_as_uint(contrib);
            __hip_atomic_store(&slots[b], payload, __ATOMIC_RELAXED, __HIP_MEMORY_SCOPE_AGENT);
        }
        // Block 0: spin-gather all 224 partials, fixed-order sum, reset, write
        if (b == 0) {
            float s = 0.f;
            #pragma unroll
            for (int k = 0; k < 4; ++k) {
                const int idx = k * 64 + l;      // 0..255
                if (idx < 224) {
                    unsigned long long v;
                    for (;;) {
                        v = __hip_atomic_load(&slots[idx], __ATOMIC_RELAXED, __HIP_MEMORY_SCOPE_AGENT);
                        if ((v >> 32) == (unsigned long long)SENT) break;
                        __builtin_amdgcn_s_sleep(1);
                    }
                    s += __uint_as_float((unsigned int)v);
                }
            }
            #pragma unroll
            for (int off = 32; off; off >>= 1) s += __shfl_xor(s, off);
            #pragma unroll
            for (int k = 0; k < 4; ++k) {        // reset for next replay
                const int idx = k * 64 + l;
                if (idx < 224)
                    __hip_atomic_store(&slots[idx], 0ull, __ATOMIC_RELAXED, __HIP_MEMORY_SCOPE_AGENT);
            }
            if (l == 0) out[0] = s;
        }
    }
}

extern "C" void kernel_launch(void* const* d_in, const int* in_sizes, int n_in,
                              void* d_out, int out_size, void* d_ws, size_t ws_size,
                              hipStream_t stream) {
    // inputs: 0=featsA(unused) 1=warpedA 2=tensorB 3=warp_grid(unused) 4=patch_size(=9)
    const float* warpedA = (const float*)d_in[1];
    const float* tensorB = (const float*)d_in[2];
    unsigned long long* slots = (unsigned long long*)d_ws;   // 224 x u64
    float* out = (float*)d_out;

    fused_kernel<<<224, 640, 0, stream>>>(warpedA, tensorB, slots, out);
}